// Round 2
// baseline (3260.908 us; speedup 1.0000x reference)
//
#include <hip/hip_runtime.h>
#include <hip/hip_bf16.h>
#include <stdint.h>

typedef __attribute__((ext_vector_type(8))) short short8;
typedef __attribute__((ext_vector_type(4))) float f32x4;

#define T_TILE  128
#define NLAYERS 16
#define T0LEN   131072
#define BATCH   8
#define RFIELD  510            // sum of dilations
#define FINLEN  130560         // 510 pool windows * 256 (usable final-layer length)

__device__ __forceinline__ unsigned short f2bf(float f) {
    unsigned u = __float_as_uint(f);
    u += 0x7FFFu + ((u >> 16) & 1u);      // round-to-nearest-even
    return (unsigned short)(u >> 16);
}

// ---- one-time weight conversion: Wd[l][o][c][tap] f32 -> wcat[l][o][k] bf16 (k = tap*64+c),
// ----                              Wr[l][r][o] f32 -> wrb same layout bf16
__global__ void prep_weights(const float* __restrict__ Wd, const float* __restrict__ Wr,
                             unsigned short* __restrict__ wcat, unsigned short* __restrict__ wrb)
{
    int idx = blockIdx.x * 256 + threadIdx.x;
    const int total1 = NLAYERS * 128 * 128;
    if (idx < total1) {
        int k = idx & 127, o = (idx >> 7) & 127, l = idx >> 14;
        int tap = k >> 6, c = k & 63;
        wcat[idx] = f2bf(Wd[(((l * 128 + o) * 64) + c) * 2 + tap]);
    } else {
        int j = idx - total1;
        if (j < NLAYERS * 64 * 128) wrb[j] = f2bf(Wr[j]);
    }
}

// ---- input 1x1 conv for a chunk: buffer row r (< len0) = original time s+r
// ---- x[b][r][c] = W0[c]*sig[b][s+r] + b0[c], layout [b][Rrows][64] f32
__global__ void input_conv(const float* __restrict__ sig, const float* __restrict__ W0,
                           const float* __restrict__ b0, float* __restrict__ x,
                           int s, int len0, int Rrows)
{
    int j = blockIdx.x * 256 + threadIdx.x;          // one float4 = 4 channels
    if (j >= len0 * 16) return;
    int b = blockIdx.y;
    int r = j >> 4, q = j & 15;
    long tg = (long)b * T0LEN + s + r;
    float sv = (s + r < T0LEN) ? sig[tg] : 0.f;
    int c = q << 2;
    f32x4 o;
    o.x = W0[c]     * sv + b0[c];
    o.y = W0[c + 1] * sv + b0[c + 1];
    o.z = W0[c + 2] * sv + b0[c + 2];
    o.w = W0[c + 3] * sv + b0[c + 3];
    ((f32x4*)(x + (long)b * Rrows * 64))[j] = o;
}

// ---- fused residual layer: relu -> dilated k=2 conv (64->128) -> relu -> 1x1 (128->64) -> +skip
__global__ __launch_bounds__(256, 2)
void layer_kernel(const float* __restrict__ xin, float* __restrict__ xout,
                  const unsigned short* __restrict__ wcat,   // [128][128] bf16, this layer
                  const unsigned short* __restrict__ wrb,    // [64][128]  bf16, this layer
                  const float* __restrict__ bd, const float* __restrict__ br,
                  int d, int Lin, int Lout, int Rrows)
{
    __shared__ unsigned short rx[256 * 64];    // relu(x) tile+halo, [t][c] bf16, swizzled (32 KB)
    __shared__ unsigned short hb[128 * 128];   // relu(h+bd) tile,  [t][o] bf16, swizzled (32 KB)

    const int tid  = threadIdx.x;
    const int lane = tid & 63;
    const int wv   = tid >> 6;       // wave 0..3
    const int l15  = lane & 15;
    const int lg   = lane >> 4;      // 0..3

    const int b  = blockIdx.y;
    const int t0 = blockIdx.x * T_TILE;
    const float* xb = xin  + (long)b * Rrows * 64;
    float*       xo = xout + (long)b * Rrows * 64;

    // ---- stage relu(x) rows t0 .. t0+T_TILE+d-1 into LDS as bf16 ----
    const int nrows = T_TILE + d;
    for (int i = tid; i < (nrows << 4); i += 256) {
        int r  = i >> 4;
        int c4 = (i & 15) << 2;
        int t  = t0 + r;
        f32x4 v = {0.f, 0.f, 0.f, 0.f};
        if (t < Lin) v = *(const f32x4*)(xb + (long)t * 64 + c4);
        unsigned p01 = (unsigned)f2bf(fmaxf(v.x, 0.f)) | ((unsigned)f2bf(fmaxf(v.y, 0.f)) << 16);
        unsigned p23 = (unsigned)f2bf(fmaxf(v.z, 0.f)) | ((unsigned)f2bf(fmaxf(v.w, 0.f)) << 16);
        int g   = c4 >> 3;
        int idx = (r << 6) + (((g ^ (r & 7)) << 3) | (c4 & 7));
        uint2 pk; pk.x = p01; pk.y = p23;
        *(uint2*)&rx[idx] = pk;
    }

    // ---- preload MFMA A-fragments (weights) from global (L2-resident) ----
    short8 a1[2][4];   // GEMM1: wave's M range = [wv*32, wv*32+32)
    #pragma unroll
    for (int m = 0; m < 2; ++m)
        #pragma unroll
        for (int k = 0; k < 4; ++k)
            a1[m][k] = *(const short8*)(wcat + ((wv * 32 + m * 16 + l15) << 7) + (k << 5) + (lg << 3));
    short8 a2[4];      // GEMM2: wave's M range = [wv*16, wv*16+16)
    #pragma unroll
    for (int k = 0; k < 4; ++k)
        a2[k] = *(const short8*)(wrb + ((wv * 16 + l15) << 7) + (k << 5) + (lg << 3));

    __syncthreads();

    // ---- GEMM1: H[o][t] = sum_k Wcat[o][k] * RX[k][t]  (k<64: tap t, k>=64: tap t+d) ----
    f32x4 acc[2][8] = {};
    #pragma unroll
    for (int k = 0; k < 4; ++k) {
        const int roff = (k >> 1) ? d : 0;
        const int g    = ((k & 1) << 2) + lg;   // channel 16B-group 0..7
        #pragma unroll
        for (int n = 0; n < 8; ++n) {
            int r = n * 16 + l15 + roff;
            short8 bf = *(const short8*)&rx[(r << 6) + ((g ^ (r & 7)) << 3)];
            acc[0][n] = __builtin_amdgcn_mfma_f32_16x16x32_bf16(a1[0][k], bf, acc[0][n], 0, 0, 0);
            acc[1][n] = __builtin_amdgcn_mfma_f32_16x16x32_bf16(a1[1][k], bf, acc[1][n], 0, 0, 0);
        }
    }

    // ---- epilogue 1: +bd, relu, bf16 -> hb[t][o] swizzled ----
    #pragma unroll
    for (int m = 0; m < 2; ++m) {
        const int o0 = wv * 32 + m * 16 + lg * 4;
        f32x4 bd4 = *(const f32x4*)(bd + o0);
        const int gg = o0 >> 3;
        #pragma unroll
        for (int n = 0; n < 8; ++n) {
            int t = n * 16 + l15;
            f32x4 h = acc[m][n];
            unsigned q01 = (unsigned)f2bf(fmaxf(h.x + bd4.x, 0.f)) | ((unsigned)f2bf(fmaxf(h.y + bd4.y, 0.f)) << 16);
            unsigned q23 = (unsigned)f2bf(fmaxf(h.z + bd4.z, 0.f)) | ((unsigned)f2bf(fmaxf(h.w + bd4.w, 0.f)) << 16);
            int idx = (t << 7) + (((gg ^ (t & 15)) << 3) | (o0 & 7));
            uint2 pk; pk.x = q01; pk.y = q23;
            *(uint2*)&hb[idx] = pk;
        }
    }
    __syncthreads();

    // ---- GEMM2: Y[r][t] = sum_o Wr[r][o] * Hb[o][t] ----
    f32x4 acc2[8] = {};
    #pragma unroll
    for (int k = 0; k < 4; ++k) {
        const int g = (k << 2) + lg;   // o 16B-group 0..15
        #pragma unroll
        for (int n = 0; n < 8; ++n) {
            int t = n * 16 + l15;
            short8 bf = *(const short8*)&hb[(t << 7) + ((g ^ (t & 15)) << 3)];
            acc2[n] = __builtin_amdgcn_mfma_f32_16x16x32_bf16(a2[k], bf, acc2[n], 0, 0, 0);
        }
    }

    // ---- epilogue 2: +br +skip(x[t+d]) in f32, store x' ----
    const int c0 = wv * 16 + lg * 4;
    f32x4 brv = *(const f32x4*)(br + c0);
    #pragma unroll
    for (int n = 0; n < 8; ++n) {
        int t = t0 + n * 16 + l15;
        if (t < Lout) {
            f32x4 sk = *(const f32x4*)(xb + (long)(t + d) * 64 + c0);
            f32x4 o = acc2[n];
            o.x += brv.x + sk.x;  o.y += brv.y + sk.y;
            o.z += brv.z + sk.z;  o.w += brv.w + sk.w;
            *(f32x4*)(xo + (long)t * 64 + c0) = o;
        }
    }
}

// ---- final 1x1 conv + AvgPool(256, stride 256) for a chunk ----
__global__ void final_pool(const float* __restrict__ x, const float* __restrict__ Wf,
                           const float* __restrict__ bf, float* __restrict__ out,
                           int s, int Rrows)
{
    __shared__ float red[4];
    int b  = blockIdx.y;
    int p  = blockIdx.x;                 // chunk-local window
    int tl = threadIdx.x;
    long base = (long)b * Rrows * 64 + (long)(p * 256 + tl) * 64;
    float dot = 0.f;
    #pragma unroll
    for (int c = 0; c < 64; c += 4) {
        f32x4 v = *(const f32x4*)(x + base + c);
        f32x4 w = *(const f32x4*)(Wf + c);
        dot += v.x * w.x + v.y * w.y + v.z * w.z + v.w * w.w;
    }
    #pragma unroll
    for (int off = 32; off > 0; off >>= 1) dot += __shfl_down(dot, off, 64);
    if ((tl & 63) == 0) red[tl >> 6] = dot;
    __syncthreads();
    if (tl == 0) out[b * 510 + (s >> 8) + p] = (red[0] + red[1] + red[2] + red[3]) * (1.0f / 256.0f) + bf[0];
}

extern "C" void kernel_launch(void* const* d_in, const int* in_sizes, int n_in,
                              void* d_out, int out_size, void* d_ws, size_t ws_size,
                              hipStream_t stream) {
    const float* sig = (const float*)d_in[0];
    const float* W0  = (const float*)d_in[1];
    const float* b0  = (const float*)d_in[2];
    const float* Wd  = (const float*)d_in[3];
    const float* bd  = (const float*)d_in[4];
    const float* Wr  = (const float*)d_in[5];
    const float* br  = (const float*)d_in[6];
    const float* Wf  = (const float*)d_in[7];
    const float* bf  = (const float*)d_in[8];
    float* out = (float*)d_out;

    // ---- workspace layout: weights FIRST (small, guaranteed in-bounds), then chunk buffers ----
    char* ws = (char*)d_ws;
    const size_t WCAT_E = (size_t)NLAYERS * 128 * 128;           // bf16 elements
    const size_t WRB_E  = (size_t)NLAYERS * 64 * 128;
    const size_t WBYTES = (WCAT_E + WRB_E) * 2;                  // 786432, 1KB-aligned
    unsigned short* wcat = (unsigned short*)ws;
    unsigned short* wrb  = (unsigned short*)(ws + WCAT_E * 2);

    if (ws_size < WBYTES + (size_t)766 * BATCH * 64 * 4 * 2) return;  // can't run at all

    // choose chunk size CH (multiple of 256) so two f32 buffers of (CH+RFIELD) rows fit
    size_t avail   = ws_size - WBYTES;
    long   rowsMax = (long)(avail / ((size_t)2 * BATCH * 64 * 4));   // rows per buffer
    long   CH      = ((rowsMax - RFIELD) / 256) * 256;
    if (CH > FINLEN) CH = FINLEN;
    if (CH < 256)    CH = 256;
    const long Rrows = CH + RFIELD;                                   // buffer capacity rows/batch

    float* xA = (float*)(ws + WBYTES);
    float* xB = xA + (size_t)BATCH * Rrows * 64;

    // weights -> bf16 (once per call; deterministic)
    const int totw = (int)(WCAT_E + WRB_E);
    prep_weights<<<(totw + 255) / 256, 256, 0, stream>>>(Wd, Wr, wcat, wrb);

    float* bufs[2] = {xA, xB};
    for (long s = 0; s < FINLEN; s += CH) {
        long CHc  = (FINLEN - s < CH) ? (FINLEN - s) : CH;   // multiple of 256
        int  len0 = (int)(CHc + RFIELD);

        dim3 gi((len0 * 16 + 255) / 256, BATCH);
        input_conv<<<gi, 256, 0, stream>>>(sig, W0, b0, xA, (int)s, len0, (int)Rrows);

        int cur = 0;
        int L = len0;
        for (int i = 0; i < NLAYERS; ++i) {
            int d = 1 << (i & 7);
            int Lout = L - d;
            dim3 grid((Lout + T_TILE - 1) / T_TILE, BATCH);
            layer_kernel<<<grid, 256, 0, stream>>>(bufs[cur], bufs[cur ^ 1],
                                                   wcat + (size_t)i * 128 * 128,
                                                   wrb  + (size_t)i * 64 * 128,
                                                   bd + i * 128, br + i * 64,
                                                   d, L, Lout, (int)Rrows);
            cur ^= 1;
            L = Lout;
        }
        // L == CHc: final conv + pool for this chunk
        dim3 g2((unsigned)(CHc / 256), BATCH);
        final_pool<<<g2, 256, 0, stream>>>(bufs[cur], Wf, bf, out, (int)s, (int)Rrows);
    }
}

// Round 3
// 2208.748 us; speedup vs baseline: 1.4764x; 1.4764x over previous
//
#include <hip/hip_runtime.h>
#include <hip/hip_bf16.h>
#include <stdint.h>

typedef __attribute__((ext_vector_type(8))) short short8;
typedef __attribute__((ext_vector_type(4))) float f32x4;
typedef unsigned short bfu;

#define T_TILE  128
#define NLAYERS 16
#define T0LEN   131072
#define BATCH   8
#define RFIELD  510            // sum of dilations
#define FINLEN  130560         // 510 pool windows * 256

__device__ __forceinline__ bfu f2bf(float f) {
    unsigned u = __float_as_uint(f);
    u += 0x7FFFu + ((u >> 16) & 1u);      // RNE
    return (bfu)(u >> 16);
}
__device__ __forceinline__ float bf2f(bfu h) { return __uint_as_float(((unsigned)h) << 16); }
// packed relu on two bf16 in a u32: zero any half with sign bit set
__device__ __forceinline__ unsigned relu2(unsigned w) {
    return w & ~(((w >> 15) & 0x00010001u) * 0xFFFFu);
}

// ---- weights: Wd[l][o][c][tap] -> wcat[l][o][k] bf16 (k=tap*64+c); Wr -> wrb bf16
__global__ void prep_weights(const float* __restrict__ Wd, const float* __restrict__ Wr,
                             bfu* __restrict__ wcat, bfu* __restrict__ wrb)
{
    int idx = blockIdx.x * 256 + threadIdx.x;
    const int total1 = NLAYERS * 128 * 128;
    if (idx < total1) {
        int k = idx & 127, o = (idx >> 7) & 127, l = idx >> 14;
        int tap = k >> 6, c = k & 63;
        wcat[idx] = f2bf(Wd[(((l * 128 + o) * 64) + c) * 2 + tap]);
    } else {
        int j = idx - total1;
        if (j < NLAYERS * 64 * 128) wrb[j] = f2bf(Wr[j]);
    }
}

// MODE: 0 = middle layer, 1 = first layer (input conv fused), 2 = last layer (final conv+pool fused)
template <int MODE>
__global__ __launch_bounds__(256, 2)
void layer_kernel(const bfu* __restrict__ xin, bfu* __restrict__ xout,
                  const bfu* __restrict__ wcat, const bfu* __restrict__ wrb,
                  const float* __restrict__ bd, const float* __restrict__ br,
                  const float* __restrict__ sig, const float* __restrict__ W0,
                  const float* __restrict__ b0, const float* __restrict__ Wf,
                  float* __restrict__ partial,
                  int s, int d, int Lin, int Lout, int Rrows)
{
    extern __shared__ bfu rx[];                // (T_TILE+d) rows x 64 ch, swizzled
    __shared__ bfu hb[128 * 128];              // 128 rows x 128 ch, swizzled (32 KB)

    const int tid  = threadIdx.x;
    const int lane = tid & 63;
    const int wv   = tid >> 6;
    const int l15  = lane & 15;
    const int lg   = lane >> 4;

    const int b  = blockIdx.y;
    const int t0 = blockIdx.x * T_TILE;
    const bfu* xb = xin  + (long)b * Rrows * 64;
    bfu*       xo = xout + (long)b * Rrows * 64;

    // ---- stage relu(x) rows [t0, t0+T_TILE+d) as bf16, swizzled [t][c] ----
    const int nrows = T_TILE + d;
    if constexpr (MODE == 1) {
        for (int i = tid; i < (nrows << 3); i += 256) {
            int r = i >> 3, oc = i & 7;
            int t = t0 + r;
            float sv = (t < Lin) ? sig[(long)b * T0LEN + s + t] : 0.f;
            unsigned pk[4];
            #pragma unroll
            for (int kk = 0; kk < 4; ++kk) {
                int c = oc * 8 + kk * 2;
                float f0 = fmaxf(W0[c]     * sv + b0[c],     0.f);
                float f1 = fmaxf(W0[c + 1] * sv + b0[c + 1], 0.f);
                pk[kk] = (unsigned)f2bf(f0) | ((unsigned)f2bf(f1) << 16);
            }
            uint4 u; u.x = pk[0]; u.y = pk[1]; u.z = pk[2]; u.w = pk[3];
            *(uint4*)&rx[(r << 6) + ((oc ^ (r & 7)) << 3)] = u;
        }
    } else {
        for (int i = tid; i < (nrows << 3); i += 256) {
            int r = i >> 3, oc = i & 7;
            int t = t0 + r;
            uint4 v = {0u, 0u, 0u, 0u};
            if (t < Lin) v = *(const uint4*)(xb + (long)t * 64 + oc * 8);
            v.x = relu2(v.x); v.y = relu2(v.y); v.z = relu2(v.z); v.w = relu2(v.w);
            *(uint4*)&rx[(r << 6) + ((oc ^ (r & 7)) << 3)] = v;
        }
    }

    // ---- weight A-fragments ----
    short8 a1[2][4];
    #pragma unroll
    for (int m = 0; m < 2; ++m)
        #pragma unroll
        for (int k = 0; k < 4; ++k)
            a1[m][k] = *(const short8*)(wcat + ((wv * 32 + m * 16 + l15) << 7) + (k << 5) + (lg << 3));
    short8 a2[4];
    #pragma unroll
    for (int k = 0; k < 4; ++k)
        a2[k] = *(const short8*)(wrb + ((wv * 16 + l15) << 7) + (k << 5) + (lg << 3));

    __syncthreads();

    // ---- GEMM1: H[o][t] = sum_k Wcat[o][k] * RX[k][t] ----
    f32x4 acc[2][8] = {};
    #pragma unroll
    for (int k = 0; k < 4; ++k) {
        const int roff = (k >> 1) ? d : 0;
        const int g    = ((k & 1) << 2) + lg;
        #pragma unroll
        for (int n = 0; n < 8; ++n) {
            int r = n * 16 + l15 + roff;
            short8 bf = *(const short8*)&rx[(r << 6) + ((g ^ (r & 7)) << 3)];
            acc[0][n] = __builtin_amdgcn_mfma_f32_16x16x32_bf16(a1[0][k], bf, acc[0][n], 0, 0, 0);
            acc[1][n] = __builtin_amdgcn_mfma_f32_16x16x32_bf16(a1[1][k], bf, acc[1][n], 0, 0, 0);
        }
    }

    // ---- epilogue 1: +bd, relu, bf16 -> hb swizzled ----
    #pragma unroll
    for (int m = 0; m < 2; ++m) {
        const int o0 = wv * 32 + m * 16 + lg * 4;
        f32x4 bd4 = *(const f32x4*)(bd + o0);
        const int gg = o0 >> 3;
        #pragma unroll
        for (int n = 0; n < 8; ++n) {
            int t = n * 16 + l15;
            f32x4 h = acc[m][n];
            unsigned q01 = (unsigned)f2bf(fmaxf(h.x + bd4.x, 0.f)) | ((unsigned)f2bf(fmaxf(h.y + bd4.y, 0.f)) << 16);
            unsigned q23 = (unsigned)f2bf(fmaxf(h.z + bd4.z, 0.f)) | ((unsigned)f2bf(fmaxf(h.w + bd4.w, 0.f)) << 16);
            int idx = (t << 7) + (((gg ^ (t & 15)) << 3) | (o0 & 7));
            uint2 pk; pk.x = q01; pk.y = q23;
            *(uint2*)&hb[idx] = pk;
        }
    }
    __syncthreads();

    // ---- GEMM2: Y[r][t] = sum_o Wr[r][o] * Hb[o][t] ----
    f32x4 acc2[8] = {};
    #pragma unroll
    for (int k = 0; k < 4; ++k) {
        const int g = (k << 2) + lg;
        #pragma unroll
        for (int n = 0; n < 8; ++n) {
            int t = n * 16 + l15;
            short8 bf = *(const short8*)&hb[(t << 7) + ((g ^ (t & 15)) << 3)];
            acc2[n] = __builtin_amdgcn_mfma_f32_16x16x32_bf16(a2[k], bf, acc2[n], 0, 0, 0);
        }
    }

    // ---- epilogue 2: +br +skip; store bf16 (MODE 0/1) or fused Wf-dot partial (MODE 2) ----
    const int c0 = wv * 16 + lg * 4;
    f32x4 brv = *(const f32x4*)(br + c0);
    float psum = 0.f;
    #pragma unroll
    for (int n = 0; n < 8; ++n) {
        int t = t0 + n * 16 + l15;
        if (t < Lout) {
            float s0, s1, s2, s3;
            if constexpr (MODE == 1) {
                float sv = sig[(long)b * T0LEN + s + t + d];
                s0 = W0[c0] * sv + b0[c0];       s1 = W0[c0 + 1] * sv + b0[c0 + 1];
                s2 = W0[c0 + 2] * sv + b0[c0 + 2]; s3 = W0[c0 + 3] * sv + b0[c0 + 3];
            } else {
                uint2 sk = *(const uint2*)(xb + (long)(t + d) * 64 + c0);
                s0 = bf2f((bfu)(sk.x & 0xFFFF)); s1 = bf2f((bfu)(sk.x >> 16));
                s2 = bf2f((bfu)(sk.y & 0xFFFF)); s3 = bf2f((bfu)(sk.y >> 16));
            }
            float y0 = acc2[n].x + brv.x + s0;
            float y1 = acc2[n].y + brv.y + s1;
            float y2 = acc2[n].z + brv.z + s2;
            float y3 = acc2[n].w + brv.w + s3;
            if constexpr (MODE == 2) {
                psum += Wf[c0] * y0 + Wf[c0 + 1] * y1 + Wf[c0 + 2] * y2 + Wf[c0 + 3] * y3;
            } else {
                uint2 pk;
                pk.x = (unsigned)f2bf(y0) | ((unsigned)f2bf(y1) << 16);
                pk.y = (unsigned)f2bf(y2) | ((unsigned)f2bf(y3) << 16);
                *(uint2*)(xo + (long)t * 64 + c0) = pk;
            }
        }
    }
    if constexpr (MODE == 2) {
        #pragma unroll
        for (int off = 32; off > 0; off >>= 1) psum += __shfl_down(psum, off, 64);
        __shared__ float red[4];
        if (lane == 0) red[wv] = psum;
        __syncthreads();
        if (tid == 0)
            partial[(long)b * 1024 + ((s + t0) >> 7)] = red[0] + red[1] + red[2] + red[3];
    }
}

// ---- final: out[b][w] = (part[2w] + part[2w+1])/256 + bf ----
__global__ void pool_reduce(const float* __restrict__ part, const float* __restrict__ bf,
                            float* __restrict__ out)
{
    int i = blockIdx.x * 256 + threadIdx.x;
    if (i >= BATCH * 510) return;
    int b = i / 510, w = i % 510;
    out[i] = (part[(long)b * 1024 + 2 * w] + part[(long)b * 1024 + 2 * w + 1]) * (1.0f / 256.0f) + bf[0];
}

extern "C" void kernel_launch(void* const* d_in, const int* in_sizes, int n_in,
                              void* d_out, int out_size, void* d_ws, size_t ws_size,
                              hipStream_t stream) {
    const float* sig = (const float*)d_in[0];
    const float* W0  = (const float*)d_in[1];
    const float* b0  = (const float*)d_in[2];
    const float* Wd  = (const float*)d_in[3];
    const float* bd  = (const float*)d_in[4];
    const float* Wr  = (const float*)d_in[5];
    const float* br  = (const float*)d_in[6];
    const float* Wf  = (const float*)d_in[7];
    const float* bf  = (const float*)d_in[8];
    float* out = (float*)d_out;

    // ---- workspace: [wcat | wrb | partial | xA | xB] ----
    char* ws = (char*)d_ws;
    const size_t WCAT_E = (size_t)NLAYERS * 128 * 128;
    const size_t WRB_E  = (size_t)NLAYERS * 64 * 128;
    const size_t WBYTES = (WCAT_E + WRB_E) * 2;          // 786432
    const size_t PARTB  = (size_t)BATCH * 1024 * 4;      // 32768
    bfu*   wcat    = (bfu*)ws;
    bfu*   wrb     = (bfu*)(ws + WCAT_E * 2);
    float* partial = (float*)(ws + WBYTES);

    if (ws_size < WBYTES + PARTB + (size_t)2 * BATCH * 766 * 64 * 2) return;

    size_t avail   = ws_size - WBYTES - PARTB;
    long   rowsMax = (long)(avail / ((size_t)2 * BATCH * 64 * 2));
    long   CH      = ((rowsMax - RFIELD) / 256) * 256;
    if (CH > FINLEN) CH = FINLEN;
    if (CH < 256)    CH = 256;
    const long Rrows = CH + RFIELD;

    bfu* xA = (bfu*)(ws + WBYTES + PARTB);
    bfu* xB = xA + (size_t)BATCH * Rrows * 64;

    const int totw = (int)(WCAT_E + WRB_E);
    prep_weights<<<(totw + 255) / 256, 256, 0, stream>>>(Wd, Wr, wcat, wrb);

    bfu* bufs[2] = {xA, xB};
    for (long s = 0; s < FINLEN; s += CH) {
        long CHc  = (FINLEN - s < CH) ? (FINLEN - s) : CH;   // multiple of 256
        int  len0 = (int)(CHc + RFIELD);

        int cur = 0;
        int L = len0;
        for (int i = 0; i < NLAYERS; ++i) {
            int d = 1 << (i & 7);
            int Lout = L - d;
            dim3 grid((Lout + T_TILE - 1) / T_TILE, BATCH);
            size_t smem = (size_t)(T_TILE + d) * 64 * 2;     // rx bytes
            const bfu* xi = bufs[cur];
            bfu*       xo = bufs[cur ^ 1];
            const bfu* wc = wcat + (size_t)i * 128 * 128;
            const bfu* wr2 = wrb + (size_t)i * 64 * 128;
            const float* bdl = bd + i * 128;
            const float* brl = br + i * 64;
            if (i == 0)
                layer_kernel<1><<<grid, 256, smem, stream>>>(xi, xo, wc, wr2, bdl, brl,
                    sig, W0, b0, Wf, partial, (int)s, d, L, Lout, (int)Rrows);
            else if (i == NLAYERS - 1)
                layer_kernel<2><<<grid, 256, smem, stream>>>(xi, xo, wc, wr2, bdl, brl,
                    sig, W0, b0, Wf, partial, (int)s, d, L, Lout, (int)Rrows);
            else
                layer_kernel<0><<<grid, 256, smem, stream>>>(xi, xo, wc, wr2, bdl, brl,
                    sig, W0, b0, Wf, partial, (int)s, d, L, Lout, (int)Rrows);
            cur ^= 1;
            L = Lout;
        }
    }
    pool_reduce<<<(BATCH * 510 + 255) / 256, 256, 0, stream>>>(partial, bf, out);
}